// Round 3
// baseline (220.053 us; speedup 1.0000x reference)
//
#include <hip/hip_runtime.h>
#include <math.h>

// Problem constants: x is [B=16, H=64, W=64, G*C=512], G=8, C=64.
#define BATCH        16
#define NPAIR        36       // upper-triangular 8x8 pairs
#define F4_PER_POS   128      // 512 floats / 4
#define F4_PER_GROUP 16       // 64 floats / 4
#define SLOTS_PER_B  65536    // HW * 16 float4-slots per batch
#define XB_F4        524288   // HW * 128 float4 per batch
#define BLOCKS_PER_B 64
#define NBLOCKS      (BATCH * BLOCKS_PER_B)   // 1024

// ---------------------------------------------------------------------------
// Kernel A: per-block partial Gram. Each block owns partials[blockIdx*36..+36]
// (no atomics, no zero-init). grid = 1024, block = 256, 4 float4/thread.
// ---------------------------------------------------------------------------
__global__ __launch_bounds__(256) void gram_kernel(const float* __restrict__ xf,
                                                   float* __restrict__ partials) {
    const float4* x = (const float4*)xf;
    const int b   = blockIdx.x >> 6;   // 64 blocks per batch
    const int blk = blockIdx.x & 63;
    const float4* xb = x + (long)b * XB_F4;

    float acc[NPAIR];
#pragma unroll
    for (int p = 0; p < NPAIR; ++p) acc[p] = 0.f;

#pragma unroll
    for (int it = 0; it < 4; ++it) {
        const int t   = blk * 1024 + it * 256 + threadIdx.x;  // slot in batch
        const int pos = t >> 4;
        const int c4  = t & 15;
        const float4* ptr = xb + pos * F4_PER_POS + c4;
        float4 xg[8];
#pragma unroll
        for (int g = 0; g < 8; ++g) xg[g] = ptr[g * F4_PER_GROUP];
        int p = 0;
#pragma unroll
        for (int g = 0; g < 8; ++g) {
#pragma unroll
            for (int gp = g; gp < 8; ++gp, ++p) {
                acc[p] += xg[g].x * xg[gp].x + xg[g].y * xg[gp].y +
                          xg[g].z * xg[gp].z + xg[g].w * xg[gp].w;
            }
        }
    }

    // wave butterfly reduction (wave = 64)
#pragma unroll
    for (int p = 0; p < NPAIR; ++p) {
        float v = acc[p];
#pragma unroll
        for (int off = 32; off; off >>= 1) v += __shfl_xor(v, off, 64);
        acc[p] = v;
    }

    __shared__ float red[4][NPAIR];
    const int lane = threadIdx.x & 63;
    const int wave = threadIdx.x >> 6;
    if (lane == 0) {
#pragma unroll
        for (int p = 0; p < NPAIR; ++p) red[wave][p] = acc[p];
    }
    __syncthreads();
    if (threadIdx.x < NPAIR) {
        partials[blockIdx.x * NPAIR + threadIdx.x] =
            red[0][threadIdx.x] + red[1][threadIdx.x] +
            red[2][threadIdx.x] + red[3][threadIdx.x];
    }
}

// ---------------------------------------------------------------------------
// Kernel B: reduce this batch's 64 partials (9 KB, L2-hot), solve the 8-wide
// routing fixed point redundantly per block, then write the alpha-weighted
// group sum over the same slots kernel A read (L3-warm).
// grid = 1024, block = 256, 4 float4/thread.
// ---------------------------------------------------------------------------
__global__ __launch_bounds__(256) void out_kernel(const float* __restrict__ xf,
                                                  const float* __restrict__ partials,
                                                  float* __restrict__ outf) {
    const float4* x = (const float4*)xf;
    float4* out = (float4*)outf;
    const int b   = blockIdx.x >> 6;
    const int blk = blockIdx.x & 63;
    const float4* xb = x + (long)b * XB_F4;

    __shared__ float Sred[NPAIR];
    __shared__ float alpha1s[8];
    __shared__ float alpha2s[8];

    if (threadIdx.x < NPAIR) {
        float s = 0.f;
        const float* pb = partials + (long)b * BLOCKS_PER_B * NPAIR + threadIdx.x;
#pragma unroll 8
        for (int j = 0; j < BLOCKS_PER_B; ++j) s += pb[j * NPAIR];
        Sred[threadIdx.x] = s;
    }
    __syncthreads();

    const int g = threadIdx.x;
    float row[8];
    float beta1 = 0.f;
    if (g < 8) {
#pragma unroll
        for (int gp = 0; gp < 8; ++gp) {
            const int a  = g < gp ? g : gp;
            const int bb = g < gp ? gp : g;
            const int idx = a * 8 - (a * (a - 1)) / 2 + (bb - a);
            row[gp] = Sred[idx];
            beta1 += row[gp];
        }
        beta1 *= 0.5f;
        alpha1s[g] = 1.f / (1.f + expf(-beta1));
    }
    __syncthreads();
    if (g < 8) {
        float beta2 = beta1;
#pragma unroll
        for (int gp = 0; gp < 8; ++gp) beta2 += alpha1s[gp] * row[gp];
        alpha2s[g] = 1.f / (1.f + expf(-beta2));
    }
    __syncthreads();

    float a[8];
#pragma unroll
    for (int gg = 0; gg < 8; ++gg) a[gg] = alpha2s[gg];

#pragma unroll
    for (int it = 0; it < 4; ++it) {
        const int t   = blk * 1024 + it * 256 + threadIdx.x;
        const int pos = t >> 4;
        const int c4  = t & 15;
        const float4* ptr = xb + pos * F4_PER_POS + c4;
        float4 accv = make_float4(0.f, 0.f, 0.f, 0.f);
#pragma unroll
        for (int gg = 0; gg < 8; ++gg) {
            const float4 v = ptr[gg * F4_PER_GROUP];
            accv.x += a[gg] * v.x;
            accv.y += a[gg] * v.y;
            accv.z += a[gg] * v.z;
            accv.w += a[gg] * v.w;
        }
        out[(long)b * SLOTS_PER_B + t] = accv;
    }
}

extern "C" void kernel_launch(void* const* d_in, const int* in_sizes, int n_in,
                              void* d_out, int out_size, void* d_ws, size_t ws_size,
                              hipStream_t stream) {
    const float* x = (const float*)d_in[0];
    float* out = (float*)d_out;
    float* partials = (float*)d_ws;   // 1024 * 36 floats = 147 KB

    gram_kernel<<<NBLOCKS, 256, 0, stream>>>(x, partials);
    out_kernel<<<NBLOCKS, 256, 0, stream>>>(x, partials, out);
}